// Round 1
// baseline (15712.869 us; speedup 1.0000x reference)
//
#include <hip/hip_runtime.h>
#include <hip/hip_bf16.h>

// ---------------------------------------------------------------------------
// 2-layer tanh RNN + FC head on MI355X (gfx950).
// Round 1: bf16 MFMA everywhere (f32 accum), multi-launch recurrence.
//   B=64 S=512 I=256 H=1024 O=256
//   pre0 = x@W_ih0^T + b        (MFMA GEMM, f32 out)
//   h0_t = tanh(pre0_t + h0_{t-1}@W_hh0^T)   x512 launches (bf16 stored)
//   pre1 = h0@W_ih1^T + b       (reuses pre buffer)
//   h1_t = tanh(pre1_t + h1_{t-1}@W_hh1^T)   x512 (reuses hseq buffer)
//   out  = h1@fc_w^T + fc_b     (f32 out)
// ---------------------------------------------------------------------------

typedef __attribute__((ext_vector_type(4))) float f32x4;
typedef __attribute__((ext_vector_type(8))) short bf16x8;
typedef __attribute__((ext_vector_type(4))) int   i32x4;
typedef __attribute__((ext_vector_type(4))) short s16x4;

#define B_  64
#define S_  512
#define I_  256
#define H_  1024
#define O_  256
#define M_  (B_ * S_)     // 32768
#define SH_ (S_ * H_)     // 524288 (row stride of h-seq in elements)

static __device__ __forceinline__ unsigned short f2bf(float f) {
  union { float f; unsigned u; } v; v.f = f;
  unsigned r = v.u + 0x7fffu + ((v.u >> 16) & 1u);   // RNE
  return (unsigned short)(r >> 16);
}

static __device__ __forceinline__ float tanh_fast(float x) {
  // tanh(x) = 1 - 2/(exp(2x)+1); saturates correctly for large |x|
  float e = __expf(2.f * x);
  return 1.f - 2.f / (e + 1.f);
}

// ---------------- f32 -> bf16 conversion (vectorized) ----------------------
__global__ void cvt_bf16(const float* __restrict__ src,
                         unsigned short* __restrict__ dst, int n4) {
  int i = blockIdx.x * blockDim.x + threadIdx.x;
  if (i < n4) {
    f32x4 v = ((const f32x4*)src)[i];
    s16x4 o;
    o[0] = (short)f2bf(v[0]); o[1] = (short)f2bf(v[1]);
    o[2] = (short)f2bf(v[2]); o[3] = (short)f2bf(v[3]);
    ((s16x4*)dst)[i] = o;
  }
}

// ---------------- big MFMA GEMM: C[M,N] = A[M,K]@W[N,K]^T + b1 (+b2) -------
// 128x128 tile, BK=32, 256 thr (4 waves, each 64x64 quadrant of 16x16 tiles).
// LDS rows padded +8 shorts (16B) -> 2-way-max bank aliasing (free).
__global__ __launch_bounds__(256)
void gemm_bf16(const unsigned short* __restrict__ A,
               const unsigned short* __restrict__ W,
               const float* __restrict__ b1, const float* __restrict__ b2,
               float* __restrict__ C, int Mx, int Nx, int Kx) {
  __shared__ __align__(16) unsigned short As[128 * 40];
  __shared__ __align__(16) unsigned short Bs[128 * 40];
  const int tid  = threadIdx.x;
  const int m0   = blockIdx.y * 128;
  const int n0   = blockIdx.x * 128;
  const int w    = tid >> 6, lane = tid & 63;
  const int quad = lane >> 4, l15 = lane & 15;
  const int wm = (w & 1) * 64, wn = (w >> 1) * 64;

  f32x4 acc[4][4] = {};

  for (int k0 = 0; k0 < Kx; k0 += 32) {
#pragma unroll
    for (int i = 0; i < 2; ++i) {   // stage A and B tiles (16B per thread x2)
      int c = tid + i * 256;
      int row = c >> 2, kc = c & 3;
      *(i32x4*)&As[row * 40 + kc * 8] =
          *(const i32x4*)&A[(size_t)(m0 + row) * Kx + k0 + kc * 8];
      *(i32x4*)&Bs[row * 40 + kc * 8] =
          *(const i32x4*)&W[(size_t)(n0 + row) * Kx + k0 + kc * 8];
    }
    __syncthreads();
    bf16x8 af[4], bg[4];
#pragma unroll
    for (int im = 0; im < 4; ++im)
      af[im] = *(const bf16x8*)&As[(wm + im * 16 + l15) * 40 + quad * 8];
#pragma unroll
    for (int in = 0; in < 4; ++in)
      bg[in] = *(const bf16x8*)&Bs[(wn + in * 16 + l15) * 40 + quad * 8];
#pragma unroll
    for (int im = 0; im < 4; ++im)
#pragma unroll
      for (int in = 0; in < 4; ++in)
        acc[im][in] = __builtin_amdgcn_mfma_f32_16x16x32_bf16(
            af[im], bg[in], acc[im][in], 0, 0, 0);
    __syncthreads();
  }

#pragma unroll
  for (int in = 0; in < 4; ++in) {
    int n = n0 + wn + in * 16 + l15;
    float bv = b1[n];
    if (b2) bv += b2[n];
#pragma unroll
    for (int im = 0; im < 4; ++im) {
      int mb = m0 + wm + im * 16 + quad * 4;   // C/D: row = quad*4+reg, col = l15
#pragma unroll
      for (int r = 0; r < 4; ++r)
        C[(size_t)(mb + r) * Nx + n] = acc[im][in][r] + bv;
    }
  }
}

// ---------------- one recurrence step ------------------------------------
// h_t[64,1024] = tanh(pre_t + h_{t-1} @ W_hh^T), stored bf16 into hseq[:,t,:].
// Grid 32 WGs x 128 thr: WG tile 64(m) x 32(n); wave = 32x32 (2x2 MFMA tiles).
// hprev/hout rows are strided by SH_ (h-seq layout [B,S,H]).
__global__ __launch_bounds__(128)
void rnn_step(const unsigned short* __restrict__ hprev,  // +b*SH_, or null (t=0)
              const float* __restrict__ pre_t,           // +b*SH_ + n
              const unsigned short* __restrict__ Whh,    // [H,H] bf16
              unsigned short* __restrict__ hout_t)       // +b*SH_ + n
{
  __shared__ __align__(16) unsigned short As[64 * 40];
  __shared__ __align__(16) unsigned short Bs[32 * 40];
  const int tid  = threadIdx.x;
  const int n0   = blockIdx.x * 32;
  const int w    = tid >> 6, lane = tid & 63;
  const int quad = lane >> 4, l15 = lane & 15;
  const int mbase = w * 32;

  f32x4 acc[2][2] = {};

  for (int k0 = 0; k0 < H_; k0 += 32) {
#pragma unroll
    for (int i = 0; i < 2; ++i) {              // A: 64 rows x 32 k
      int c = tid + i * 128;
      int row = c >> 2, kc = c & 3;
      i32x4 v = {};
      if (hprev)
        v = *(const i32x4*)&hprev[(size_t)row * SH_ + k0 + kc * 8];
      *(i32x4*)&As[row * 40 + kc * 8] = v;
    }
    {                                          // B: 32 W rows x 32 k
      int row = tid >> 2, kc = tid & 3;
      *(i32x4*)&Bs[row * 40 + kc * 8] =
          *(const i32x4*)&Whh[(size_t)(n0 + row) * H_ + k0 + kc * 8];
    }
    __syncthreads();
    bf16x8 af[2], bg[2];
#pragma unroll
    for (int im = 0; im < 2; ++im)
      af[im] = *(const bf16x8*)&As[(mbase + im * 16 + l15) * 40 + quad * 8];
#pragma unroll
    for (int in = 0; in < 2; ++in)
      bg[in] = *(const bf16x8*)&Bs[(in * 16 + l15) * 40 + quad * 8];
#pragma unroll
    for (int im = 0; im < 2; ++im)
#pragma unroll
      for (int in = 0; in < 2; ++in)
        acc[im][in] = __builtin_amdgcn_mfma_f32_16x16x32_bf16(
            af[im], bg[in], acc[im][in], 0, 0, 0);
    __syncthreads();
  }

#pragma unroll
  for (int im = 0; im < 2; ++im) {
    int m = mbase + im * 16 + quad * 4;        // m == batch index b
#pragma unroll
    for (int in = 0; in < 2; ++in) {
      int n = n0 + in * 16 + l15;
#pragma unroll
      for (int r = 0; r < 4; ++r) {
        int b = m + r;
        float x = pre_t[(size_t)b * SH_ + n] + acc[im][in][r];
        hout_t[(size_t)b * SH_ + n] = f2bf(tanh_fast(x));
      }
    }
  }
}

// ---------------------------------------------------------------------------
extern "C" void kernel_launch(void* const* d_in, const int* in_sizes, int n_in,
                              void* d_out, int out_size, void* d_ws, size_t ws_size,
                              hipStream_t stream) {
  const float* x      = (const float*)d_in[0];
  const float* W_ih_0 = (const float*)d_in[1];
  const float* W_hh_0 = (const float*)d_in[2];
  const float* b_ih_0 = (const float*)d_in[3];
  const float* b_hh_0 = (const float*)d_in[4];
  const float* W_ih_1 = (const float*)d_in[5];
  const float* W_hh_1 = (const float*)d_in[6];
  const float* b_ih_1 = (const float*)d_in[7];
  const float* b_hh_1 = (const float*)d_in[8];
  const float* fc_w   = (const float*)d_in[9];
  const float* fc_b   = (const float*)d_in[10];
  float* out = (float*)d_out;

  // workspace layout (bytes), all offsets 256-aligned
  char* ws = (char*)d_ws;
  size_t off = 0;
  auto alloc = [&](size_t bytes) { char* p = ws + off; off += (bytes + 255) & ~(size_t)255; return p; };
  unsigned short* xb    = (unsigned short*)alloc((size_t)M_ * I_ * 2);   // 16 MB
  unsigned short* wih0b = (unsigned short*)alloc((size_t)H_ * I_ * 2);
  unsigned short* whh0b = (unsigned short*)alloc((size_t)H_ * H_ * 2);
  unsigned short* wih1b = (unsigned short*)alloc((size_t)H_ * H_ * 2);
  unsigned short* whh1b = (unsigned short*)alloc((size_t)H_ * H_ * 2);
  unsigned short* fcwb  = (unsigned short*)alloc((size_t)O_ * H_ * 2);
  float*          pre   = (float*)alloc((size_t)M_ * H_ * 4);            // 128 MB (pre0 then pre1)
  unsigned short* hseq  = (unsigned short*)alloc((size_t)M_ * H_ * 2);   // 64 MB (h0 then h1)

  // ---- convert inputs to bf16 ----
  auto cvt = [&](const float* s, unsigned short* d, int n) {
    int n4 = n / 4;
    cvt_bf16<<<(n4 + 255) / 256, 256, 0, stream>>>(s, d, n4);
  };
  cvt(x,      xb,    M_ * I_);
  cvt(W_ih_0, wih0b, H_ * I_);
  cvt(W_hh_0, whh0b, H_ * H_);
  cvt(W_ih_1, wih1b, H_ * H_);
  cvt(W_hh_1, whh1b, H_ * H_);
  cvt(fc_w,   fcwb,  O_ * H_);

  // ---- layer 0: input projection ----
  gemm_bf16<<<dim3(H_ / 128, M_ / 128), 256, 0, stream>>>(
      xb, wih0b, b_ih_0, b_hh_0, pre, M_, H_, I_);

  // ---- layer 0: recurrence ----
  for (int t = 0; t < S_; ++t) {
    const unsigned short* hp = (t == 0) ? nullptr : hseq + (size_t)(t - 1) * H_;
    rnn_step<<<32, 128, 0, stream>>>(hp, pre + (size_t)t * H_, whh0b,
                                     hseq + (size_t)t * H_);
  }

  // ---- layer 1: input projection (pre buffer reused; h0 is the A operand) --
  gemm_bf16<<<dim3(H_ / 128, M_ / 128), 256, 0, stream>>>(
      hseq, wih1b, b_ih_1, b_hh_1, pre, M_, H_, H_);

  // ---- layer 1: recurrence (hseq buffer reused for h1) ----
  for (int t = 0; t < S_; ++t) {
    const unsigned short* hp = (t == 0) ? nullptr : hseq + (size_t)(t - 1) * H_;
    rnn_step<<<32, 128, 0, stream>>>(hp, pre + (size_t)t * H_, whh1b,
                                     hseq + (size_t)t * H_);
  }

  // ---- FC head ----
  gemm_bf16<<<dim3(O_ / 128, M_ / 128), 256, 0, stream>>>(
      hseq, fcwb, fc_b, nullptr, out, M_, O_, H_);
}

// Round 2
// 3263.015 us; speedup vs baseline: 4.8154x; 4.8154x over previous
//
#include <hip/hip_runtime.h>
#include <hip/hip_bf16.h>

// ---------------------------------------------------------------------------
// 2-layer tanh RNN + FC head on MI355X (gfx950).
// Round 2: persistent recurrence kernel (flag-synced, W_hh register-stationary,
// batch-split into 4 independent groups of 16), replacing 1024 tiny launches.
//   B=64 S=512 I=256 H=1024 O=256
// ---------------------------------------------------------------------------

typedef __attribute__((ext_vector_type(4))) float f32x4;
typedef __attribute__((ext_vector_type(8))) short bf16x8;
typedef __attribute__((ext_vector_type(4))) int   i32x4;
typedef __attribute__((ext_vector_type(4))) short s16x4;

#define B_  64
#define S_  512
#define I_  256
#define H_  1024
#define O_  256
#define M_  (B_ * S_)     // 32768
#define SH_ (S_ * H_)     // 524288 (row stride of h-seq / pre in elements)

static __device__ __forceinline__ unsigned short f2bf(float f) {
  union { float f; unsigned u; } v; v.f = f;
  unsigned r = v.u + 0x7fffu + ((v.u >> 16) & 1u);   // RNE
  return (unsigned short)(r >> 16);
}

static __device__ __forceinline__ float tanh_fast(float x) {
  float e = __expf(2.f * x);
  return 1.f - 2.f / (e + 1.f);
}

// ---------------- f32 -> bf16 conversion (vectorized) ----------------------
__global__ void cvt_bf16(const float* __restrict__ src,
                         unsigned short* __restrict__ dst, int n4) {
  int i = blockIdx.x * blockDim.x + threadIdx.x;
  if (i < n4) {
    f32x4 v = ((const f32x4*)src)[i];
    s16x4 o;
    o[0] = (short)f2bf(v[0]); o[1] = (short)f2bf(v[1]);
    o[2] = (short)f2bf(v[2]); o[3] = (short)f2bf(v[3]);
    ((s16x4*)dst)[i] = o;
  }
}

// ---------------- big MFMA GEMM: C[M,N] = A[M,K]@W[N,K]^T + b1 (+b2) -------
// 128x128 tile, BK=32, 256 thr (4 waves, each 64x64 quadrant of 16x16 tiles).
__global__ __launch_bounds__(256)
void gemm_bf16(const unsigned short* __restrict__ A,
               const unsigned short* __restrict__ W,
               const float* __restrict__ b1, const float* __restrict__ b2,
               float* __restrict__ C, int Mx, int Nx, int Kx) {
  __shared__ __align__(16) unsigned short As[128 * 40];
  __shared__ __align__(16) unsigned short Bs[128 * 40];
  const int tid  = threadIdx.x;
  const int m0   = blockIdx.y * 128;
  const int n0   = blockIdx.x * 128;
  const int w    = tid >> 6, lane = tid & 63;
  const int quad = lane >> 4, l15 = lane & 15;
  const int wm = (w & 1) * 64, wn = (w >> 1) * 64;

  f32x4 acc[4][4] = {};

  for (int k0 = 0; k0 < Kx; k0 += 32) {
#pragma unroll
    for (int i = 0; i < 2; ++i) {
      int c = tid + i * 256;
      int row = c >> 2, kc = c & 3;
      *(i32x4*)&As[row * 40 + kc * 8] =
          *(const i32x4*)&A[(size_t)(m0 + row) * Kx + k0 + kc * 8];
      *(i32x4*)&Bs[row * 40 + kc * 8] =
          *(const i32x4*)&W[(size_t)(n0 + row) * Kx + k0 + kc * 8];
    }
    __syncthreads();
    bf16x8 af[4], bg[4];
#pragma unroll
    for (int im = 0; im < 4; ++im)
      af[im] = *(const bf16x8*)&As[(wm + im * 16 + l15) * 40 + quad * 8];
#pragma unroll
    for (int in = 0; in < 4; ++in)
      bg[in] = *(const bf16x8*)&Bs[(wn + in * 16 + l15) * 40 + quad * 8];
#pragma unroll
    for (int im = 0; im < 4; ++im)
#pragma unroll
      for (int in = 0; in < 4; ++in)
        acc[im][in] = __builtin_amdgcn_mfma_f32_16x16x32_bf16(
            af[im], bg[in], acc[im][in], 0, 0, 0);
    __syncthreads();
  }

#pragma unroll
  for (int in = 0; in < 4; ++in) {
    int n = n0 + wn + in * 16 + l15;
    float bv = b1[n];
    if (b2) bv += b2[n];
#pragma unroll
    for (int im = 0; im < 4; ++im) {
      int mb = m0 + wm + im * 16 + quad * 4;   // C/D: row = quad*4+reg, col = l15
#pragma unroll
      for (int r = 0; r < 4; ++r)
        C[(size_t)(mb + r) * Nx + n] = acc[im][in][r] + bv;
    }
  }
}

// ---------------- persistent recurrence kernel -----------------------------
// h_t = tanh(pre_t + h_{t-1} @ W_hh^T) for t=0..S-1, one launch per layer.
// Grid: 64 WGs x 256 thr. Group g = bx>>4 owns batches [g*16, g*16+16) —
// groups are fully independent (batch-parallel). Member j = bx&15 owns cols
// [j*64, j*64+64). Wave w owns k-slice [w*256, w*256+256) (split-K, reduced
// through LDS). W_hh fragments live in 128 VGPRs/lane for all 512 steps.
// Sync: per-(group,step) counter; h stored with agent-scope stores so data is
// at the device coherence point before the flag add; readers spin relaxed then
// agent-acquire fence (invalidates stale L1/XCD-L2) before loading h.
__global__ __launch_bounds__(256, 1)
void rnn_persist(const unsigned short* __restrict__ Whh,  // [H,H] bf16
                 const float* __restrict__ pre,           // [B,S,H] f32
                 unsigned short* __restrict__ hseq,       // [B,S,H] bf16 out
                 unsigned int* __restrict__ flags)        // [4*S] zeroed
{
  const int bx   = blockIdx.x;
  const int g    = bx >> 4;         // group 0..3
  const int j    = bx & 15;         // member 0..15
  const int n0   = j * 64;
  const int tid  = threadIdx.x;
  const int w    = tid >> 6;        // wave 0..3 = k-slice
  const int lane = tid & 63;
  const int quad = lane >> 4, l15 = lane & 15;

  // q[w][i][col=l15][r4 padded to 20]
  __shared__ __align__(16) float q[4][4][16][20];

  // ---- preload W fragments (register-stationary for the whole t-loop) ----
  bf16x8 Wf[4][8];
  {
    const unsigned short* wp = Whh + (size_t)(n0 + l15) * H_ + w * 256 + quad * 8;
#pragma unroll
    for (int i = 0; i < 4; ++i)
#pragma unroll
      for (int kk = 0; kk < 8; ++kk)
        Wf[i][kk] = *(const bf16x8*)(wp + (size_t)i * 16 * H_ + kk * 32);
  }

  unsigned int* const gflag = flags + g * S_;

  for (int t = 0; t < S_; ++t) {
    // pre_t prefetch (independent of the recurrence — issue before the wait)
    float pv[4];
#pragma unroll
    for (int r = 0; r < 4; ++r)
      pv[r] = pre[(size_t)(g * 16 + quad * 4 + r) * SH_ + (size_t)t * H_ +
                  n0 + w * 16 + l15];

    f32x4 acc[4] = {};

    if (t > 0) {
      if (tid == 0) {
        while (__hip_atomic_load(&gflag[t - 1], __ATOMIC_RELAXED,
                                 __HIP_MEMORY_SCOPE_AGENT) < 16u) {}
        __builtin_amdgcn_fence(__ATOMIC_ACQUIRE, "agent");
      }
      __syncthreads();

      const unsigned short* hp = hseq + (size_t)(g * 16 + l15) * SH_ +
                                 (size_t)(t - 1) * H_ + w * 256 + quad * 8;
      bf16x8 Af[8];
#pragma unroll
      for (int kk = 0; kk < 8; ++kk)
        Af[kk] = *(const bf16x8*)(hp + kk * 32);
#pragma unroll
      for (int kk = 0; kk < 8; ++kk)
#pragma unroll
        for (int i = 0; i < 4; ++i)
          acc[i] = __builtin_amdgcn_mfma_f32_16x16x32_bf16(
              Af[kk], Wf[i][kk], acc[i], 0, 0, 0);
    }

    // ---- split-K partial reduce through LDS ----
#pragma unroll
    for (int i = 0; i < 4; ++i)
      *(f32x4*)&q[w][i][l15][quad * 4] = acc[i];
    __syncthreads();

    f32x4 s = {};
#pragma unroll
    for (int wp2 = 0; wp2 < 4; ++wp2) {
      f32x4 v = *(const f32x4*)&q[wp2][w][l15][quad * 4];
#pragma unroll
      for (int r = 0; r < 4; ++r) s[r] += v[r];
    }

    // ---- epilogue: +pre, tanh, agent-scope store ----
#pragma unroll
    for (int r = 0; r < 4; ++r) {
      float xv = pv[r] + s[r];
      unsigned short hb = f2bf(tanh_fast(xv));
      size_t o = (size_t)(g * 16 + quad * 4 + r) * SH_ + (size_t)t * H_ +
                 n0 + w * 16 + l15;
      __hip_atomic_store(&hseq[o], hb, __ATOMIC_RELAXED,
                         __HIP_MEMORY_SCOPE_AGENT);
    }
    __syncthreads();   // drains vmcnt(0): stores at coherence point; also WAR on q
    if (tid == 0)
      __hip_atomic_fetch_add(&gflag[t], 1u, __ATOMIC_RELAXED,
                             __HIP_MEMORY_SCOPE_AGENT);
  }
}

// ---------------------------------------------------------------------------
extern "C" void kernel_launch(void* const* d_in, const int* in_sizes, int n_in,
                              void* d_out, int out_size, void* d_ws, size_t ws_size,
                              hipStream_t stream) {
  const float* x      = (const float*)d_in[0];
  const float* W_ih_0 = (const float*)d_in[1];
  const float* W_hh_0 = (const float*)d_in[2];
  const float* b_ih_0 = (const float*)d_in[3];
  const float* b_hh_0 = (const float*)d_in[4];
  const float* W_ih_1 = (const float*)d_in[5];
  const float* W_hh_1 = (const float*)d_in[6];
  const float* b_ih_1 = (const float*)d_in[7];
  const float* b_hh_1 = (const float*)d_in[8];
  const float* fc_w   = (const float*)d_in[9];
  const float* fc_b   = (const float*)d_in[10];
  float* out = (float*)d_out;

  char* ws = (char*)d_ws;
  size_t off = 0;
  auto alloc = [&](size_t bytes) { char* p = ws + off; off += (bytes + 255) & ~(size_t)255; return p; };
  unsigned short* xb    = (unsigned short*)alloc((size_t)M_ * I_ * 2);   // 16 MB
  unsigned short* wih0b = (unsigned short*)alloc((size_t)H_ * I_ * 2);
  unsigned short* whh0b = (unsigned short*)alloc((size_t)H_ * H_ * 2);
  unsigned short* wih1b = (unsigned short*)alloc((size_t)H_ * H_ * 2);
  unsigned short* whh1b = (unsigned short*)alloc((size_t)H_ * H_ * 2);
  unsigned short* fcwb  = (unsigned short*)alloc((size_t)O_ * H_ * 2);
  unsigned int*   flags = (unsigned int*)alloc(2 * 4 * S_ * 4);          // 16 KB
  float*          pre   = (float*)alloc((size_t)M_ * H_ * 4);            // 128 MB
  unsigned short* h0seq = (unsigned short*)alloc((size_t)M_ * H_ * 2);   // 64 MB
  // separate h1 buffer if workspace allows, else reuse h0 (correct either way)
  unsigned short* h1seq;
  if (off + (size_t)M_ * H_ * 2 <= ws_size)
    h1seq = (unsigned short*)alloc((size_t)M_ * H_ * 2);                 // 64 MB
  else
    h1seq = h0seq;

  hipMemsetAsync(flags, 0, 2 * 4 * S_ * 4, stream);

  auto cvt = [&](const float* s, unsigned short* d, int n) {
    int n4 = n / 4;
    cvt_bf16<<<(n4 + 255) / 256, 256, 0, stream>>>(s, d, n4);
  };
  cvt(x,      xb,    M_ * I_);
  cvt(W_ih_0, wih0b, H_ * I_);
  cvt(W_hh_0, whh0b, H_ * H_);
  cvt(W_ih_1, wih1b, H_ * H_);
  cvt(W_hh_1, whh1b, H_ * H_);
  cvt(fc_w,   fcwb,  O_ * H_);

  // layer 0
  gemm_bf16<<<dim3(H_ / 128, M_ / 128), 256, 0, stream>>>(
      xb, wih0b, b_ih_0, b_hh_0, pre, M_, H_, I_);
  rnn_persist<<<64, 256, 0, stream>>>(whh0b, pre, h0seq, flags);

  // layer 1
  gemm_bf16<<<dim3(H_ / 128, M_ / 128), 256, 0, stream>>>(
      h0seq, wih1b, b_ih_1, b_hh_1, pre, M_, H_, H_);
  rnn_persist<<<64, 256, 0, stream>>>(whh1b, pre, h1seq, flags + 4 * S_);

  // FC head
  gemm_bf16<<<dim3(O_ / 128, M_ / 128), 256, 0, stream>>>(
      h1seq, fcwb, fc_b, nullptr, out, M_, O_, H_);
}